// Round 3
// baseline (239.548 us; speedup 1.0000x reference)
//
#include <hip/hip_runtime.h>

// EMA y_t = 0.1*x_t + 0.9*y_{t-1} along T of x[B=64][T=8192][F=64], fp32.
// R7: stop fighting the scheduler -- make load batching structural.
// R5/R6 evidence: 80us both rounds, ~2.85 TB/s combined, implied in-flight
// ~one 256B load per wave (compiler collapses scalar strided load batches
// into the serial FMA chain; VGPR 28/56 confirms). Fix: stage via 4
// INDEPENDENT global dwordx4 loads (1KB coalesced each, nothing consumes
// them for a full phase -> cannot be serialized), transpose through
// wave-PRIVATE LDS tile ([16][64] linear, conflict-free both sides,
// no __syncthreads anywhere), consume with serial FMA chain + nontemporal
// scalar stores. Depth-2 pipeline: batch k+2 loads in flight while batch
// k+1 waits/writes. 16 waves/CU, all 4096 waves co-resident, 4KB/wave in
// flight -> latency ceiling ~37 TB/s -> HBM-bound (~36us floor at 6.3TB/s
// for 229MB observed traffic).
// Geometry unchanged (validated, absmax 3.9e-3 pass): L=128 stores/chunk,
// H=64 windup, chunk 0 exact. Grid 64b x 16 = 1024 blocks x 256 thr.

typedef float fx4 __attribute__((ext_vector_type(4)));

constexpr int Tn = 8192;
constexpr int Fn = 64;    // features = lanes
constexpr int Ln = 128;   // stored rows per chunk
constexpr int Hn = 64;    // windup rows (0.9^64 ~ 1.2e-3 truncation)
constexpr int PF = 16;    // rows per staged batch (4KB tile)
constexpr float ALPHA = 0.1f;
constexpr float OMA   = 0.9f;

__global__ __launch_bounds__(256) void ema_kernel(const float* __restrict__ x,
                                                  float* __restrict__ y) {
    const int lane = threadIdx.x & 63;
    const int w    = threadIdx.x >> 6;            // wave in block 0..3
    const int b    = blockIdx.x >> 4;             // 0..63
    const int c    = ((blockIdx.x & 15) << 2) | w; // chunk 0..63

    const size_t bb = (size_t)b * (Tn * Fn);
    const float* __restrict__ xp = x + bb;
    float*       __restrict__ yp = y + bb;

    // wave-private double-buffered tile: [wave][buf][16 rows][64 feats]
    __shared__ float lds[4][2][PF * Fn];
    float (* __restrict__ Lb)[PF * Fn] = lds[w];

    const int lr = lane >> 4;          // row-sub 0..3 within a 1KB load
    const int lf = (lane & 15) << 2;   // feature offset 0,4,..,60

    const int tstart = (c == 0) ? 0 : c * Ln - Hn;   // first staged row
    const int nb     = (c == 0) ? Ln / PF : (Ln + Hn) / PF; // 8 or 12
    const int sb     = (c == 0) ? 0 : Hn / PF;       // first stored batch

    // 4 independent coalesced 1KB loads: rows t0+4j+lr, feats lf..lf+3
    auto LOADG = [&](int t0, fx4& g0, fx4& g1, fx4& g2, fx4& g3) {
        const float* p = xp + (size_t)(t0 + lr) * Fn + lf;
        g0 = *(const fx4*)(p);
        g1 = *(const fx4*)(p + 4 * Fn);
        g2 = *(const fx4*)(p + 8 * Fn);
        g3 = *(const fx4*)(p + 12 * Fn);
    };
    // write staged regs into a [16][64] linear tile (1KB contiguous per
    // ds_write_b128 instruction -> conflict-free)
    auto WRITE = [&](float* buf, fx4 g0, fx4 g1, fx4 g2, fx4 g3) {
        float* q = buf + lr * Fn + lf;
        *(fx4*)(q)          = g0;
        *(fx4*)(q + 4 * Fn) = g1;
        *(fx4*)(q + 8 * Fn) = g2;
        *(fx4*)(q + 12 * Fn) = g3;
    };
    float s = 0.0f;
    // consume one tile: serial EMA chain, optional stores, optional exact
    // first row (chunk 0: y_0 = x_0)
    auto CONSUME = [&](const float* buf, int bt, bool dostore, bool first) {
        int i0 = 0;
        if (first) {
            s = buf[lane];
            __builtin_nontemporal_store(s, &yp[(size_t)bt * Fn + lane]);
            i0 = 1;
        }
        #pragma unroll
        for (int i = 0; i < PF; ++i) {
            if (i < i0) continue;
            s = fmaf(OMA, s, ALPHA * buf[i * Fn + lane]);
            if (dostore)
                __builtin_nontemporal_store(s, &yp[(size_t)(bt + i) * Fn + lane]);
        }
    };

    fx4 a0, a1, a2, a3, b0, b1, b2, b3;

    // prologue: tile0 staged, tile1 in flight
    LOADG(tstart, a0, a1, a2, a3);
    WRITE(Lb[0], a0, a1, a2, a3);
    LOADG(tstart + PF, b0, b1, b2, b3);

    int k = 0;
    while (true) {
        // even k: consume buf0; batch k+1 is in regs b*, k+2 -> a*
        CONSUME(Lb[0], tstart + k * PF, k >= sb, (c == 0) && (k == 0));
        if (k + 1 >= nb) break;
        WRITE(Lb[1], b0, b1, b2, b3);
        if (k + 2 < nb) LOADG(tstart + (k + 2) * PF, a0, a1, a2, a3);
        ++k;
        // odd k: consume buf1; batch k+1 is in regs a*, k+2 -> b*
        CONSUME(Lb[1], tstart + k * PF, k >= sb, false);
        if (k + 1 >= nb) break;
        WRITE(Lb[0], a0, a1, a2, a3);
        if (k + 2 < nb) LOADG(tstart + (k + 2) * PF, b0, b1, b2, b3);
        ++k;
    }
}

extern "C" void kernel_launch(void* const* d_in, const int* in_sizes, int n_in,
                              void* d_out, int out_size, void* d_ws, size_t ws_size,
                              hipStream_t stream) {
    const float* x = (const float*)d_in[0];
    float*       y = (float*)d_out;
    // 64 b * 64 chunks = 4096 wave-streams; 4 waves (256 thr) per block;
    // all 4096 waves co-resident (16 waves/CU, 128KB LDS of 160).
    ema_kernel<<<dim3(1024), dim3(256), 0, stream>>>(x, y);
}